// Round 4
// baseline (2147.363 us; speedup 1.0000x reference)
//
#include <hip/hip_runtime.h>
#include <hip/hip_bf16.h>
#include <math.h>

// TransformerEncoder (Shaw relative attention), MI355X gfx950.
// GEMMs: C = A @ B^T. gemm_bd: 128x128 tile, BK=64; A staged via double-buffered
// swizzled global_load_lds (1-deep pipeline, 1 barrier/iter), B direct global->VGPR
// fragments (halves LDS traffic vs m97 structure). gemm_bt: legacy 128x64 for N=64.
// Attention scores flow bf16 (S1 = qk^T, S2 = rel term), fused add+softmax.

typedef __hip_bfloat16 bf16;
typedef short short8 __attribute__((ext_vector_type(8)));
typedef float f32x4 __attribute__((ext_vector_type(4)));

constexpr int Lc = 512;      // sequence length (also S)
constexpr int Bc = 8;        // batch
constexpr int Ec = 1024;     // embed
constexpr int Hc = 16;       // heads
constexpr int HDc = 64;      // head dim
constexpr int NLc = 2;       // layers
constexpr int DFFc = 4096;   // ffn dim
constexpr int LB = Lc * Bc;  // 4096 tokens
constexpr int BHc = Bc * Hc; // 128
constexpr float EPSc = 1e-5f;

__device__ inline unsigned short f2bfu(float f) {
  union { __hip_bfloat16 h; unsigned short u; } cv;
  cv.h = __float2bfloat16(f);
  return cv.u;
}
__device__ inline float bfu2f(unsigned short u) {
  union { unsigned int i; float f; } cv;
  cv.i = (unsigned int)u << 16;
  return cv.f;
}

// async 16B global -> LDS (lds dest wave-uniform; HW adds lane*16)
__device__ inline void async16(const bf16* gsrc, bf16* ldst) {
  __builtin_amdgcn_global_load_lds(
      (const __attribute__((address_space(1))) void*)gsrc,
      (__attribute__((address_space(3))) void*)ldst, 16, 0, 0);
}

// ---------------------------------------------------------------------------
// gemm_bd: C[z][M,N] = A[z][M,K] @ B[z][N,K]^T (+bias) (+=C) (gelu) (bf16 out)
// 128x128 tile, BK=64, 256 thr (4 waves, 64x64 each, 4x4 16x16x32 frags).
// A: double-buffered LDS, XOR-chunk swizzle (2-way-only bank aliasing).
// B: direct global->VGPR fragments, prefetched one k-iter ahead.
// Pipeline: sync_k certifies A_k staged AND iter k-1 reads done; then issue
// A_{k+1}/B_{k+1} (fly during MFMA_k) so next sync's vmcnt drain is ~free.
// Requires M%128==0, N%128==0, K%64==0, rows 16B-aligned.
// ---------------------------------------------------------------------------
template <bool ACC, bool GELU, bool OBF>
__global__ __launch_bounds__(256) void gemm_bd(
    int M, int N, int K,
    const bf16* __restrict__ A, long long lda, long long sAz,
    const bf16* __restrict__ Bm, long long ldb, long long sBz,
    void* __restrict__ Cv, long long ldc, long long sCz,
    const float* __restrict__ bias) {
  __shared__ __align__(16) bf16 As[2][128 * 64];
  const int tid = threadIdx.x;
  const int w = tid >> 6, lane = tid & 63, quad = lane >> 4, lr = lane & 15;
  const int wm = w >> 1, wn = w & 1;
  const int m0 = blockIdx.x * 128, n0 = blockIdx.y * 128;
  const long long z = blockIdx.z;
  const bf16* Az = A + z * sAz;
  const bf16* Bz = Bm + z * sBz;
  float* Cf = (float*)Cv;
  bf16* Cb = (bf16*)Cv;

  // A staging: within an 8-row (1 KB) group, lane = srow*8 + sj; lane holds
  // stored-chunk sj of row srow => global chunk sc = sj ^ srow.
  const int srow = lane >> 3, sj = lane & 7, sc = sj ^ srow;
  const bf16* ast[4];
#pragma unroll
  for (int s = 0; s < 4; s++) {
    int li = w * 4 + s;
    ast[s] = Az + (long long)(m0 + li * 8 + srow) * lda + sc * 8;
  }
  // B fragment pointers: lane reads B[n0 + wn*64 + j*16 + lr][k + quad*8]
  const bf16* bptr[4];
#pragma unroll
  for (int j = 0; j < 4; j++)
    bptr[j] = Bz + (long long)(n0 + wn * 64 + j * 16 + lr) * ldb + quad * 8;

  short8 breg[2][8];  // [parity][j*2 + kshalf]
  const int nIter = K >> 6;

  // prologue: stage A_0, load B_0
#pragma unroll
  for (int s = 0; s < 4; s++) async16(ast[s], &As[0][(w * 4 + s) * 512]);
#pragma unroll
  for (int j = 0; j < 4; j++) {
    breg[0][j * 2 + 0] = *(const short8*)(bptr[j] + 0);
    breg[0][j * 2 + 1] = *(const short8*)(bptr[j] + 32);
  }

  f32x4 acc[4][4];
#pragma unroll
  for (int i = 0; i < 4; i++)
#pragma unroll
    for (int j = 0; j < 4; j++) acc[i][j] = {0.f, 0.f, 0.f, 0.f};

  for (int k = 0; k < nIter; ++k) {
    const int p = k & 1;
    __syncthreads();  // A_k fully staged (all waves); iter k-1 reads retired
    if (k + 1 < nIter) {
      const long long ko = (long long)(k + 1) * 64;
#pragma unroll
      for (int s = 0; s < 4; s++)
        async16(ast[s] + ko, &As[p ^ 1][(w * 4 + s) * 512]);
#pragma unroll
      for (int j = 0; j < 4; j++) {
        breg[p ^ 1][j * 2 + 0] = *(const short8*)(bptr[j] + ko);
        breg[p ^ 1][j * 2 + 1] = *(const short8*)(bptr[j] + ko + 32);
      }
    }
#pragma unroll
    for (int ks2 = 0; ks2 < 2; ks2++) {
      const int jc = (ks2 * 4 + quad) ^ (lr & 7);  // swizzled chunk slot
      short8 a[4];
#pragma unroll
      for (int i = 0; i < 4; i++) {
        int row = wm * 64 + i * 16 + lr;
        a[i] = *(const short8*)&As[p][row * 64 + jc * 8];
      }
#pragma unroll
      for (int i = 0; i < 4; i++)
#pragma unroll
        for (int j = 0; j < 4; j++)
          acc[i][j] = __builtin_amdgcn_mfma_f32_16x16x32_bf16(a[i], breg[p][j * 2 + ks2], acc[i][j], 0, 0, 0);
    }
  }

  // epilogue: D row = quad*4+r, col = lane&15 (verified gfx950 C/D layout)
#pragma unroll
  for (int j = 0; j < 4; j++) {
    int col = n0 + wn * 64 + j * 16 + lr;
    float bv = bias ? bias[col] : 0.f;
#pragma unroll
    for (int i = 0; i < 4; i++) {
#pragma unroll
      for (int r = 0; r < 4; r++) {
        int row = m0 + wm * 64 + i * 16 + quad * 4 + r;
        long long off = z * sCz + (long long)row * ldc + col;
        float v = acc[i][j][r] + bv;
        if (ACC) v += Cf[off];
        if (GELU) v = 0.5f * v * (1.f + erff(v * 0.70710678118654752f));
        if (OBF)
          Cb[off] = __float2bfloat16(v);
        else
          Cf[off] = v;
      }
    }
  }
}

// ---------------------------------------------------------------------------
// Legacy batched GEMM for N=64 outputs: tile 128x64, BK=64, 256 threads.
// ---------------------------------------------------------------------------
template <bool ACC, bool GELU, bool OBF>
__global__ __launch_bounds__(256) void gemm_bt(
    int M, int N, int K,
    const bf16* __restrict__ A, int lda, long long sAz,
    const bf16* __restrict__ Bm, int ldb, long long sBz,
    void* __restrict__ Cv, int ldc, long long sCz,
    const float* __restrict__ bias) {
  __shared__ __align__(16) bf16 As[128 * 72];
  __shared__ __align__(16) bf16 Bs[64 * 72];
  const int tid = threadIdx.x;
  const int w = tid >> 6, lane = tid & 63, quad = lane >> 4, lr = lane & 15;
  const int m0 = blockIdx.x * 128, n0 = blockIdx.y * 64;
  const long long z = blockIdx.z;
  A += z * sAz;
  Bm += z * sBz;
  float* Cf = (float*)Cv;
  bf16* Cb = (bf16*)Cv;

  f32x4 acc[2][4];
#pragma unroll
  for (int i = 0; i < 2; i++)
#pragma unroll
    for (int j = 0; j < 4; j++) acc[i][j] = {0.f, 0.f, 0.f, 0.f};

  for (int k0 = 0; k0 < K; k0 += 64) {
#pragma unroll
    for (int i = 0; i < 8; i++) {
      int slot = tid + i * 256;
      int r = slot >> 4, c4 = (slot & 15) << 2;
      *(ushort4*)&As[r * 72 + c4] = *(const ushort4*)(A + (long long)(m0 + r) * lda + k0 + c4);
    }
#pragma unroll
    for (int i = 0; i < 4; i++) {
      int slot = tid + i * 256;
      int r = slot >> 4, c4 = (slot & 15) << 2;
      *(ushort4*)&Bs[r * 72 + c4] = *(const ushort4*)(Bm + (long long)(n0 + r) * ldb + k0 + c4);
    }
    __syncthreads();
#pragma unroll
    for (int ks = 0; ks < 64; ks += 32) {
      short8 a[2], b[4];
#pragma unroll
      for (int i = 0; i < 2; i++)
        a[i] = *(const short8*)&As[(w * 32 + i * 16 + lr) * 72 + ks + quad * 8];
#pragma unroll
      for (int j = 0; j < 4; j++)
        b[j] = *(const short8*)&Bs[(j * 16 + lr) * 72 + ks + quad * 8];
#pragma unroll
      for (int i = 0; i < 2; i++)
#pragma unroll
        for (int j = 0; j < 4; j++)
          acc[i][j] = __builtin_amdgcn_mfma_f32_16x16x32_bf16(a[i], b[j], acc[i][j], 0, 0, 0);
    }
    __syncthreads();
  }

#pragma unroll
  for (int i = 0; i < 2; i++) {
#pragma unroll
    for (int j = 0; j < 4; j++) {
      int col = n0 + j * 16 + lr;
      float bv = bias ? bias[col] : 0.f;
#pragma unroll
      for (int r = 0; r < 4; r++) {
        int row = m0 + w * 32 + i * 16 + quad * 4 + r;
        long long off = z * sCz + (long long)row * ldc + col;
        float v = acc[i][j][r] + bv;
        if (ACC) v += Cf[off];
        if (GELU) v = 0.5f * v * (1.f + erff(v * 0.70710678118654752f));
        if (OBF)
          Cb[off] = __float2bfloat16(v);
        else
          Cf[off] = v;
      }
    }
  }
}

// ---------------------------------------------------------------------------
__global__ void cvt_bf16(const float* __restrict__ in, bf16* __restrict__ out, long long n) {
  long long i = (long long)blockIdx.x * 256 + threadIdx.x;
  if (i < n) out[i] = __float2bfloat16(in[i]);
}

__global__ void init_x(const float* __restrict__ src, float* __restrict__ x, bf16* __restrict__ xb) {
  long long i = (long long)blockIdx.x * 256 + threadIdx.x;
  float v = src[i];
  x[i] = v;
  xb[i] = __float2bfloat16(v);
}

// R = pos + typ -> Rb[l,s,d] bf16 and Rt[l,d,s] bf16. grid (L/64 s-tiles, L), 256 thr
__global__ void prep_R(const float* __restrict__ pos, const float* __restrict__ typ,
                       bf16* __restrict__ Rb, bf16* __restrict__ Rt) {
  __shared__ __align__(16) float Ls[64 * 68];
  int l = blockIdx.y, s0 = blockIdx.x * 64;
  int tid = threadIdx.x;
#pragma unroll
  for (int i = 0; i < 4; i++) {
    int slot = tid + i * 256;
    int r = slot >> 4, c = (slot & 15) << 2;
    long long off = (((long long)l) * Lc + s0 + r) * HDc + c;
    float4 a = *(const float4*)&pos[off];
    float4 b = *(const float4*)&typ[off];
    float4 s = {a.x + b.x, a.y + b.y, a.z + b.z, a.w + b.w};
    *(float4*)&Ls[r * 68 + c] = s;
    ushort4 o = {f2bfu(s.x), f2bfu(s.y), f2bfu(s.z), f2bfu(s.w)};
    *(ushort4*)&Rb[off] = o;
  }
  __syncthreads();
#pragma unroll
  for (int i = 0; i < 4; i++) {
    int slot = tid + i * 256;
    int d = slot >> 4, s4 = (slot & 15) << 2;
    ushort4 o = {f2bfu(Ls[(s4 + 0) * 68 + d]), f2bfu(Ls[(s4 + 1) * 68 + d]),
                 f2bfu(Ls[(s4 + 2) * 68 + d]), f2bfu(Ls[(s4 + 3) * 68 + d])};
    *(ushort4*)&Rt[(((long long)l) * HDc + d) * Lc + s0 + s4] = o;
  }
}

// P[L*B, 3E] bf16 -> q,k bf16 in [B,H,L,HD]; q scaled by HD^-0.5. 4 elems/thread.
__global__ void split_qk(const bf16* __restrict__ P, bf16* __restrict__ q, bf16* __restrict__ k) {
  long long i4 = (long long)blockIdx.x * 256 + threadIdx.x;  // over L*B*E/4
  int col = (int)(i4 & 255) << 2;
  long long row = i4 >> 8;
  int l = (int)(row >> 3), b = (int)(row & 7);
  int h = col >> 6, d = col & 63;
  ushort4 qv = *(const ushort4*)&P[row * 3072 + col];
  ushort4 kv = *(const ushort4*)&P[row * 3072 + Ec + col];
  ushort4 qs = {f2bfu(bfu2f(qv.x) * 0.125f), f2bfu(bfu2f(qv.y) * 0.125f),
                f2bfu(bfu2f(qv.z) * 0.125f), f2bfu(bfu2f(qv.w) * 0.125f)};
  long long dst = (((long long)(b * Hc + h)) * Lc + l) * HDc + d;
  *(ushort4*)&q[dst] = qs;
  *(ushort4*)&k[dst] = kv;
}

// P v-part bf16 -> vt[b,h,d,l] bf16 via LDS transpose. grid (L/64, BH), 256 thr
__global__ void transpose_v(const bf16* __restrict__ P, bf16* __restrict__ vt) {
  __shared__ __align__(16) unsigned short Ls[64 * 72];
  int bh = blockIdx.y, b = bh >> 4, h = bh & 15;
  int l0 = blockIdx.x * 64;
  int tid = threadIdx.x;
#pragma unroll
  for (int i = 0; i < 4; i++) {
    int slot = tid + i * 256;
    int r = slot >> 4, c4 = (slot & 15) << 2;
    *(ushort4*)&Ls[r * 72 + c4] =
        *(const ushort4*)&P[((long long)(l0 + r) * Bc + b) * 3072 + 2 * Ec + h * 64 + c4];
  }
  __syncthreads();
#pragma unroll
  for (int i = 0; i < 4; i++) {
    int slot = tid + i * 256;
    int d = slot >> 4, s4 = (slot & 15) << 2;
    ushort4 o = {Ls[(s4 + 0) * 72 + d], Ls[(s4 + 1) * 72 + d],
                 Ls[(s4 + 2) * 72 + d], Ls[(s4 + 3) * 72 + d]};
    *(ushort4*)&vt[(((long long)(b * Hc + h)) * HDc + d) * Lc + l0 + s4] = o;
  }
}

// probs = softmax(S1 + S2) row-wise; S1 [bh*512+l, 512] bf16 (overwritten in place),
// S2 [(l*128+bh), 512] bf16. One wave per row, 4 rows/block.
__global__ __launch_bounds__(256) void softmax_add(bf16* S1, const bf16* __restrict__ S2) {
  int w = threadIdx.x >> 6, lane = threadIdx.x & 63;
  long long row = (long long)blockIdx.x * 4 + w;
  int bh = (int)(row >> 9), l = (int)(row & 511);
  bf16* r1 = S1 + row * 512;
  const bf16* r2 = S2 + ((long long)l * BHc + bh) * 512;
  ushort4 a0 = *(const ushort4*)((const unsigned short*)r1 + lane * 4);
  ushort4 a1 = *(const ushort4*)((const unsigned short*)r1 + 256 + lane * 4);
  ushort4 b0 = *(const ushort4*)((const unsigned short*)r2 + lane * 4);
  ushort4 b1 = *(const ushort4*)((const unsigned short*)r2 + 256 + lane * 4);
  float v[8] = {bfu2f(a0.x) + bfu2f(b0.x), bfu2f(a0.y) + bfu2f(b0.y),
                bfu2f(a0.z) + bfu2f(b0.z), bfu2f(a0.w) + bfu2f(b0.w),
                bfu2f(a1.x) + bfu2f(b1.x), bfu2f(a1.y) + bfu2f(b1.y),
                bfu2f(a1.z) + bfu2f(b1.z), bfu2f(a1.w) + bfu2f(b1.w)};
  float mx = v[0];
#pragma unroll
  for (int e = 1; e < 8; e++) mx = fmaxf(mx, v[e]);
#pragma unroll
  for (int o = 32; o; o >>= 1) mx = fmaxf(mx, __shfl_xor(mx, o, 64));
  float sum = 0.f;
#pragma unroll
  for (int e = 0; e < 8; e++) {
    v[e] = __expf(v[e] - mx);
    sum += v[e];
  }
#pragma unroll
  for (int o = 32; o; o >>= 1) sum += __shfl_xor(sum, o, 64);
  float inv = 1.f / sum;
  ushort4 o0 = {f2bfu(v[0] * inv), f2bfu(v[1] * inv), f2bfu(v[2] * inv), f2bfu(v[3] * inv)};
  ushort4 o1 = {f2bfu(v[4] * inv), f2bfu(v[5] * inv), f2bfu(v[6] * inv), f2bfu(v[7] * inv)};
  *(ushort4*)((unsigned short*)r1 + lane * 4) = o0;
  *(ushort4*)((unsigned short*)r1 + 256 + lane * 4) = o1;
}

// ao2[B,H,L,HD] fp32 -> aob[(l*B+b), h*64+d] bf16
__global__ void merge_ao(const float* __restrict__ ao2, bf16* __restrict__ aob) {
  long long i = (long long)blockIdx.x * 256 + threadIdx.x;
  int d = (int)(i & 63);
  long long t = i >> 6;
  int l = (int)(t & (Lc - 1));
  long long bh = t >> 9;
  int b = (int)(bh >> 4), h = (int)(bh & 15);
  aob[((long long)(l * Bc + b)) * Ec + h * 64 + d] = __float2bfloat16(ao2[i]);
}

// x_out = LN(x + c) * g + be; writes fp32 (outF) and bf16 (outB). one row/block
__global__ __launch_bounds__(256) void add_ln(const float* __restrict__ X, const float* __restrict__ Cin,
                                              const float* __restrict__ g, const float* __restrict__ be,
                                              float* __restrict__ outF, bf16* __restrict__ outB) {
  __shared__ float s_sum[4], s_sq[4];
  long long row = blockIdx.x;
  int tid = threadIdx.x;
  float4 xv = *(const float4*)&X[row * Ec + tid * 4];
  float4 cv = *(const float4*)&Cin[row * Ec + tid * 4];
  float v[4] = {xv.x + cv.x, xv.y + cv.y, xv.z + cv.z, xv.w + cv.w};
  float sm = v[0] + v[1] + v[2] + v[3];
  float sq = v[0] * v[0] + v[1] * v[1] + v[2] * v[2] + v[3] * v[3];
#pragma unroll
  for (int o = 32; o; o >>= 1) {
    sm += __shfl_xor(sm, o, 64);
    sq += __shfl_xor(sq, o, 64);
  }
  int w = tid >> 6, lane = tid & 63;
  if (lane == 0) {
    s_sum[w] = sm;
    s_sq[w] = sq;
  }
  __syncthreads();
  sm = s_sum[0] + s_sum[1] + s_sum[2] + s_sum[3];
  sq = s_sq[0] + s_sq[1] + s_sq[2] + s_sq[3];
  float mean = sm * (1.f / Ec);
  float var = sq * (1.f / Ec) - mean * mean;
  float rs = rsqrtf(var + EPSc);
#pragma unroll
  for (int e = 0; e < 4; e++) {
    int n = tid * 4 + e;
    float o = (v[e] - mean) * rs * g[n] + be[n];
    outF[row * Ec + n] = o;
    outB[row * Ec + n] = __float2bfloat16(o);
  }
}

// ---------------------------------------------------------------------------
static constexpr size_t WS_NEED = 327155712;

struct GlobalWs {
  void* p = nullptr;
  GlobalWs() {
    if (hipMalloc(&p, WS_NEED) != hipSuccess) p = nullptr;
  }
};
static GlobalWs g_ws;

extern "C" void kernel_launch(void* const* d_in, const int* in_sizes, int n_in,
                              void* d_out, int out_size, void* d_ws, size_t ws_size,
                              hipStream_t stream) {
  const float* src = (const float*)d_in[0];
  const float* pos = (const float*)d_in[1];
  const float* typ = (const float*)d_in[2];
  const float* Wi = (const float*)d_in[3];
  const float* bi = (const float*)d_in[4];
  const float* Wo = (const float*)d_in[5];
  const float* bo = (const float*)d_in[6];
  const float* W1 = (const float*)d_in[7];
  const float* b1 = (const float*)d_in[8];
  const float* W2 = (const float*)d_in[9];
  const float* b2 = (const float*)d_in[10];
  const float* g1 = (const float*)d_in[11];
  const float* be1 = (const float*)d_in[12];
  const float* g2 = (const float*)d_in[13];
  const float* be2 = (const float*)d_in[14];
  float* out = (float*)d_out;
  (void)in_sizes; (void)n_in; (void)out_size;

  char* wp = (ws_size >= WS_NEED) ? (char*)d_ws : (char*)g_ws.p;
  if (!wp) wp = (char*)d_ws;
  auto alloc = [&](size_t bytes) {
    char* r = wp;
    wp += (bytes + 255) & ~(size_t)255;
    return r;
  };

  // Union region U (134 MB), lifetimes: P bf16 (25 MB) -> [S1|S2] bf16 -> hb bf16
  char* U = alloc((size_t)BHc * Lc * Lc * 4);
  bf16* P = (bf16*)U;                                       // [L*B, 3E] bf16
  bf16* S1 = (bf16*)U;                                      // [bh*512+l, 512] bf16 (probs in place)
  bf16* S2 = (bf16*)(U + (size_t)BHc * Lc * Lc * 2);        // [(l*128+bh), 512] bf16
  bf16* probs = S1;
  bf16* hb = (bf16*)U;

  float* x = (float*)alloc((size_t)LB * Ec * 4);
  bf16* xb = (bf16*)alloc((size_t)LB * Ec * 2);
  bf16* q = (bf16*)alloc((size_t)BHc * Lc * HDc * 2);       // [B,H,L,HD]
  bf16* k = (bf16*)alloc((size_t)BHc * Lc * HDc * 2);
  bf16* vt = (bf16*)alloc((size_t)BHc * HDc * Lc * 2);      // [B,H,HD,L]
  float* ao2 = (float*)alloc((size_t)BHc * Lc * HDc * 4);   // attn out; aliased as c1
  float* c1 = ao2;
  bf16* aob = (bf16*)alloc((size_t)LB * Ec * 2);
  bf16* Rb = (bf16*)alloc((size_t)Lc * Lc * HDc * 2);       // R[l,s,d]
  bf16* Rt = (bf16*)alloc((size_t)Lc * HDc * Lc * 2);       // R^T[l,d,s]
  bf16* wib = (bf16*)alloc((size_t)NLc * 3 * Ec * Ec * 2);
  bf16* wob = (bf16*)alloc((size_t)NLc * Ec * Ec * 2);
  bf16* w1b = (bf16*)alloc((size_t)NLc * DFFc * Ec * 2);
  bf16* w2b = (bf16*)alloc((size_t)NLc * Ec * DFFc * 2);

  // ---- prep
  {
    long long n;
    n = (long long)NLc * 3 * Ec * Ec;
    cvt_bf16<<<(int)((n + 255) / 256), 256, 0, stream>>>(Wi, wib, n);
    n = (long long)NLc * Ec * Ec;
    cvt_bf16<<<(int)((n + 255) / 256), 256, 0, stream>>>(Wo, wob, n);
    n = (long long)NLc * DFFc * Ec;
    cvt_bf16<<<(int)((n + 255) / 256), 256, 0, stream>>>(W1, w1b, n);
    n = (long long)NLc * Ec * DFFc;
    cvt_bf16<<<(int)((n + 255) / 256), 256, 0, stream>>>(W2, w2b, n);
  }
  prep_R<<<dim3(Lc / 64, Lc), 256, 0, stream>>>(pos, typ, Rb, Rt);
  init_x<<<LB * Ec / 256, 256, 0, stream>>>(src, x, xb);

  for (int i = 0; i < NLc; i++) {
    const bf16* Wi_b = wib + (size_t)i * 3 * Ec * Ec;
    const bf16* Wo_b = wob + (size_t)i * Ec * Ec;
    const bf16* W1_b = w1b + (size_t)i * DFFc * Ec;
    const bf16* W2_b = w2b + (size_t)i * Ec * DFFc;

    // QKV projection: P = bf16(xb @ Wi^T + bi)   [4096, 3072]
    gemm_bd<false, false, true><<<dim3(LB / 128, 3 * Ec / 128, 1), 256, 0, stream>>>(
        LB, 3 * Ec, Ec, xb, Ec, 0, Wi_b, Ec, 0, P, 3 * Ec, 0, bi + (size_t)i * 3 * Ec);
    split_qk<<<LB * Ec / 4 / 256, 256, 0, stream>>>(P, q, k);
    transpose_v<<<dim3(Lc / 64, BHc), 256, 0, stream>>>(P, vt);

    // S1 = bf16(q @ k^T)  (batched over bh)   [P dead from here]
    gemm_bd<false, false, true><<<dim3(Lc / 128, Lc / 128, BHc), 256, 0, stream>>>(
        Lc, Lc, HDc, q, HDc, (long long)Lc * HDc, k, HDc, (long long)Lc * HDc,
        S1, Lc, (long long)Lc * Lc, nullptr);
    // S2 = bf16(q_l @ R_l^T)  (batched over l); M = BHc = 128
    gemm_bd<false, false, true><<<dim3(1, Lc / 128, Lc), 256, 0, stream>>>(
        BHc, Lc, HDc, q, (long long)Lc * HDc, (long long)HDc, Rb, HDc, (long long)Lc * HDc,
        S2, Lc, (long long)BHc * Lc, nullptr);

    // probs = softmax(S1 + S2), bf16, in place over S1
    softmax_add<<<BHc * Lc / 4, 256, 0, stream>>>(S1, S2);

    // ao2 = probs @ v  (v^T stored; batched over bh)  [N=64 -> legacy kernel]
    gemm_bt<false, false, false><<<dim3(Lc / 128, 1, BHc), 256, 0, stream>>>(
        Lc, HDc, Lc, probs, Lc, (long long)Lc * Lc, vt, Lc, (long long)HDc * Lc,
        ao2, HDc, (long long)Lc * HDc, nullptr);
    // ao2 += probs_l @ R_l  (R^T stored; batched over l)
    gemm_bt<true, false, false><<<dim3(1, 1, Lc), 256, 0, stream>>>(
        BHc, HDc, Lc, probs, Lc * Lc, (long long)Lc, Rt, Lc, (long long)HDc * Lc,
        ao2, Lc * HDc, (long long)HDc, nullptr);

    merge_ao<<<BHc * Lc * HDc / 256, 256, 0, stream>>>(ao2, aob);

    // output projection: c1 = aob @ Wo^T + bo   [ao2 dead; c1 aliases it]
    gemm_bd<false, false, false><<<dim3(LB / 128, Ec / 128, 1), 256, 0, stream>>>(
        LB, Ec, Ec, aob, Ec, 0, Wo_b, Ec, 0, c1, Ec, 0, bo + (size_t)i * Ec);
    add_ln<<<LB, 256, 0, stream>>>(x, c1, g1 + (size_t)i * Ec, be1 + (size_t)i * Ec, x, xb);

    // ffn1: hb = gelu(xb @ W1^T + b1)  bf16 out   [probs dead; hb aliases U]
    gemm_bd<false, true, true><<<dim3(LB / 128, DFFc / 128, 1), 256, 0, stream>>>(
        LB, DFFc, Ec, xb, Ec, 0, W1_b, Ec, 0, hb, DFFc, 0, b1 + (size_t)i * DFFc);
    // ffn2: c1 = hb @ W2^T + b2
    gemm_bd<false, false, false><<<dim3(LB / 128, Ec / 128, 1), 256, 0, stream>>>(
        LB, Ec, DFFc, hb, DFFc, 0, W2_b, DFFc, 0, c1, Ec, 0, b2 + (size_t)i * Ec);

    float* outF = (i == NLc - 1) ? out : x;
    add_ln<<<LB, 256, 0, stream>>>(x, c1, g2 + (size_t)i * Ec, be2 + (size_t)i * Ec, outF, xb);
  }
}